// Round 15
// baseline (677.583 us; speedup 1.0000x reference)
//
#include <hip/hip_runtime.h>

#define BN_EPS 1e-3f
#define NREP 16  // BN stat replicas

typedef __attribute__((ext_vector_type(8))) short short8;
typedef __attribute__((ext_vector_type(4))) float float4v;

__device__ __forceinline__ short f2bf(float f) {
    unsigned u = __float_as_uint(f);
    unsigned r = (u + 0x7FFFu + ((u >> 16) & 1u)) >> 16;
    return (short)r;
}

__device__ __forceinline__ float bf2f(short s) {
    return __uint_as_float(((unsigned)(unsigned short)s) << 16);
}

// s_waitcnt vmcnt(N) only (N up to 63: bits [3:0] and [15:14])
template <int N>
__device__ __forceinline__ void waitcnt_vm() {
    __builtin_amdgcn_s_waitcnt(0xF70 | (N & 15) | ((N >> 4) << 14));
}

// ---------------- small utility kernels ----------------

__global__ __launch_bounds__(256) void zero_kernel(float* p, int n) {
    int i = blockIdx.x * 256 + threadIdx.x;
    if (i < n) p[i] = 0.f;
}

__global__ __launch_bounds__(256) void copy_kernel(const float* __restrict__ in,
                                                   float* __restrict__ out, int n) {
    int i = blockIdx.x * 256 + threadIdx.x;
    if (i < n) out[i] = in[i];
}

__global__ __launch_bounds__(256) void zero_rows_kernel(short* a, short* b, long maxN) {
    int t = threadIdx.x;
    if (t < 32) a[maxN * 32 + t] = 0;
    else if (t < 96) a[maxN * 64 + (t - 32)] = 0;
    else if (t < 128) b[maxN * 32 + (t - 96)] = 0;
    else if (t < 192) b[maxN * 64 + (t - 128)] = 0;
}

__global__ __launch_bounds__(256) void xyz_kernel(const int* __restrict__ coords,
                                                  float* __restrict__ out, int N,
                                                  float sx, float sy, float sz) {
    int n = blockIdx.x * 256 + threadIdx.x;
    if (n >= N) return;
    int4 c = ((const int4*)coords)[n];
    out[n * 3 + 0] = c.w * sx;
    out[n * 3 + 1] = c.z * sy - 40.0f;
    out[n * 3 + 2] = c.y * sz - 3.0f;
}

__global__ __launch_bounds__(256) void convert_f0(const float* __restrict__ f,
                                                  short* __restrict__ dst, int N) {
    int i = blockIdx.x * 256 + threadIdx.x;
    if (i >= N * 32) return;
    int c = i & 31, n = i >> 5;
    dst[i] = (c < 4) ? f2bf(f[n * 4 + c]) : (short)0;
}

// ---- weight prep: W [K][CI][CO] fp32 -> Wt [K][c*CT+t][quad][l16][8] bf16 ----
struct PrepAll {
    const float* src[14];
    short* dst[14];
    int CI[14];
    int CO[14];
    int CHP[14];
    int cum[15];
};

__global__ __launch_bounds__(256) void prep_all_kernel(PrepAll d) {
    int i = blockIdx.x * 256 + threadIdx.x;
    if (i >= d.cum[14]) return;
    int l = 0;
    while (l < 13 && i >= d.cum[l + 1]) ++l;
    int f = i - d.cum[l];
    int CO = d.CO[l], CI = d.CI[l];
    int NCH = d.CHP[l] / 32, CT = CO / 16;
    int e = f & 7;
    int u = f >> 3;
    int l16 = u & 15;
    int q = (u >> 4) & 3;
    int u2 = u >> 6;
    int t = u2 % CT;
    int c = (u2 / CT) % NCH;
    int k = u2 / (CT * NCH);
    int ci = c * 32 + q * 8 + e;
    int co = t * 16 + l16;
    float v = (ci < CI) ? d.src[l][((size_t)k * CI + ci) * CO + co] : 0.f;
    d.dst[l][f] = f2bf(v);
}

// per-k A fragments for one wave (32 rows x CHP), held in VGPRs
struct ASet {
    short8 v0, v1, v2, v3;  // (mt0,c0) (mt0,c1) (mt1,c0) (mt1,c1)
};

// ---------- wave-compacted MFMA sparse conv (R13 config + DB=2 everywhere) ----------
// 64-thread (1-wave) blocks, 32 output rows each. Phase 1: stage wave's rb
// slice [K][32] in LDS, ballot-compact alive taps. Phase 2: register pipeline
// over alive taps: B 2-ahead (DB=2 now ALSO for CO=64 — R14 counters showed
// VGPR is not the binding resource at 20% occupancy, so the extra BSet is
// free), A 2-ahead, counted vmcnt per tail regime (never drain mid-loop).
// R14 A/B: XCD swizzle cut FETCH 33% but cost 4% time -> not bandwidth-bound
// at any cache level; remaining mechanism is per-tap exposed load latency,
// which DB=2 halves for the CO=64 layers. Preact stored bf16.
template <int CHP, int CO, int K>
__global__ __launch_bounds__(64, 2) void sconv_wc(const short* __restrict__ feat,
                                                  const int* __restrict__ rb,
                                                  const short* __restrict__ Wt,
                                                  short* __restrict__ out,
                                                  float* __restrict__ stats, int N, int zrow) {
    constexpr int NCH = CHP / 32;
    constexpr int CT = CO / 16;
    constexpr int BTILE = CO * CHP;  // shorts
    constexpr int BF = BTILE / 512;  // B loads per tile (1KB coalesced each)
    constexpr int A_ = 2 * NCH;      // A gather loads per tile
    constexpr int WN2 = 2 * (BF + A_);  // d>=2
    constexpr int WN1 = BF + A_;        // d==1

    __shared__ int sIdx[K * 32];
    __shared__ int sFlag[K];
    __shared__ int sKl[K];
    __shared__ int sKn;

    const int lane = threadIdx.x & 63;
    const int quad = lane >> 4;
    const int l16 = lane & 15;
    const int m0 = blockIdx.x * 32;

    if (lane < K) sFlag[lane] = 0;
    __syncthreads();
    for (int e = lane; e < K * 32; e += 64) {
        int r = m0 + (e & 31);
        int v = (r < N) ? rb[(size_t)(e >> 5) * N + r] : -1;
        sIdx[e] = v;
        if (v >= 0) sFlag[e >> 5] = 1;  // benign race: same value
    }
    __syncthreads();
    {
        int f = (lane < K) ? sFlag[lane] : 0;
        unsigned long long m = __ballot(f != 0);
        if (f) sKl[__popcll(m & ((1ull << lane) - 1ull))] = lane;
        if (lane == 0) sKn = (int)__popcll(m);
    }
    __syncthreads();
    const int nk = sKn;

    const short* fquad = feat + quad * 8;

    struct BSet {
        short8 f[BF];
    };
    auto issueB = [&](int kp) {
        BSet b;
        const short* wk = Wt + (size_t)kp * BTILE;
#pragma unroll
        for (int j = 0; j < BF; ++j)
            b.f[j] = *(const short8*)(wk + ((j * 64) + quad * 16 + l16) * 8);
        return b;
    };
    auto issueA = [&](int kp) {
        ASet s;
        int i0 = sIdx[kp * 32 + l16];
        int i1 = sIdx[kp * 32 + 16 + l16];
        const short* q0 = fquad + (size_t)(i0 < 0 ? zrow : i0) * CHP;
        const short* q1 = fquad + (size_t)(i1 < 0 ? zrow : i1) * CHP;
        s.v0 = *(const short8*)q0;
        s.v2 = *(const short8*)q1;
        if constexpr (NCH == 2) {
            s.v1 = *(const short8*)(q0 + 32);
            s.v3 = *(const short8*)(q1 + 32);
        } else {
            s.v1 = (short8)0;
            s.v3 = (short8)0;
        }
        return s;
    };

    float4v acc[2][CT];
#pragma unroll
    for (int mt = 0; mt < 2; ++mt)
#pragma unroll
        for (int t = 0; t < CT; ++t) acc[mt][t] = (float4v)0.f;

    // ---- prologue (interleaved so steady wait constants hold from i=0) ----
    BSet bA{}, bB{}, bC{};
    ASet sA{}, sB{}, sC{};
    if (nk > 0) {
        bA = issueB(sKl[0]);
        sA = issueA(sKl[0]);
    }
    if (nk > 1) {
        bB = issueB(sKl[1]);
        sB = issueA(sKl[1]);
    }

#pragma unroll 1
    for (int i = 0; i < nk; ++i) {
        if (i + 2 < nk) {
            bC = issueB(sKl[i + 2]);
            sC = issueA(sKl[i + 2]);
        }
        const int d = nk - 1 - i;
        if (d >= 2) waitcnt_vm<WN2>();
        else if (d == 1) waitcnt_vm<WN1>();
        else waitcnt_vm<0>();
#pragma unroll
        for (int c = 0; c < NCH; ++c) {
#pragma unroll
            for (int t = 0; t < CT; ++t) {
                short8 bf = bA.f[c * CT + t];
#pragma unroll
                for (int mt = 0; mt < 2; ++mt) {
                    short8 af = (mt == 0) ? ((c == 0) ? sA.v0 : sA.v1)
                                          : ((c == 0) ? sA.v2 : sA.v3);
                    acc[mt][t] =
                        __builtin_amdgcn_mfma_f32_16x16x32_bf16(af, bf, acc[mt][t], 0, 0, 0);
                }
            }
        }
        bA = bB;
        bB = bC;
        sA = sB;
        sB = sC;
    }

    // stores: D layout col = lane&15, row = quad*4 + reg. bf16 preact.
#pragma unroll
    for (int mt = 0; mt < 2; ++mt)
#pragma unroll
        for (int t = 0; t < CT; ++t) {
            int col = t * 16 + l16;
#pragma unroll
            for (int r = 0; r < 4; ++r) {
                int orow = m0 + mt * 16 + quad * 4 + r;
                if (orow < N) out[(size_t)orow * CO + col] = f2bf(acc[mt][t][r]);
            }
        }

    // per-wave BN stats (fp32 acc) -> replica atomics.
    // (OOB rows and -1 gathers hit the zero row, so their acc entries are 0)
    float* st = stats + (size_t)(blockIdx.x & (NREP - 1)) * 128;
#pragma unroll
    for (int t = 0; t < CT; ++t) {
        float s = 0.f, ss = 0.f;
#pragma unroll
        for (int mt = 0; mt < 2; ++mt)
#pragma unroll
            for (int r = 0; r < 4; ++r) {
                float v = acc[mt][t][r];
                s += v;
                ss += v * v;
            }
        s += __shfl_xor(s, 16);
        s += __shfl_xor(s, 32);
        ss += __shfl_xor(ss, 16);
        ss += __shfl_xor(ss, 32);
        if (lane < 16) {
            atomicAdd(&st[t * 16 + lane], s);
            atomicAdd(&st[64 + t * 16 + lane], ss);
        }
    }
}

// ---------------- BN apply + ReLU, 8-wide vectorized (bf16 preact in) ------------
template <int COUT, int CHPN, bool F32OUT, bool BFOUT>
__global__ __launch_bounds__(256) void bn_apply(const short* __restrict__ x,
                                                const float* __restrict__ stats,
                                                const float* __restrict__ g,
                                                const float* __restrict__ b,
                                                float* __restrict__ fout,
                                                short* __restrict__ bfout, int N) {
    constexpr int CW = BFOUT ? CHPN : COUT;
    constexpr int CV = CW / 8;  // 8-channel groups per row
    __shared__ float ssc[COUT];
    __shared__ float ssh[COUT];
    int tid = threadIdx.x;
    if (tid < COUT) {
        float s = 0.f, q = 0.f;
#pragma unroll
        for (int r = 0; r < NREP; ++r) {
            s += stats[r * 128 + tid];
            q += stats[r * 128 + 64 + tid];
        }
        float inv = 1.0f / (float)N;
        float m = s * inv;
        float v = q * inv - m * m;
        float sc = g[tid] / sqrtf(v + BN_EPS);
        ssc[tid] = sc;
        ssh[tid] = b[tid] - m * sc;
    }
    __syncthreads();
    long i = (long)blockIdx.x * 256 + tid;
    if (i >= (long)N * CV) return;
    int c8 = (int)(i % CV);
    long n = i / CV;
    int cb = c8 * 8;
    float y[8];
#pragma unroll
    for (int j = 0; j < 8; ++j) y[j] = 0.f;
    if (cb < COUT) {
        short8 xv = *(const short8*)(x + n * COUT + cb);
#pragma unroll
        for (int j = 0; j < 8; ++j)
            y[j] = fmaxf(bf2f(xv[j]) * ssc[cb + j] + ssh[cb + j], 0.f);
        if constexpr (F32OUT) {
            float* fo = fout + n * COUT + cb;
            if ((((unsigned long long)fout) & 15ull) == 0) {  // uniform branch
                float4v o0, o1;
#pragma unroll
                for (int j = 0; j < 4; ++j) {
                    o0[j] = y[j];
                    o1[j] = y[4 + j];
                }
                ((float4v*)fo)[0] = o0;
                ((float4v*)fo)[1] = o1;
            } else {
#pragma unroll
                for (int j = 0; j < 8; ++j) fo[j] = y[j];
            }
        }
    }
    if constexpr (BFOUT) {
        short8 p;
#pragma unroll
        for (int j = 0; j < 8; ++j) p[j] = f2bf(y[j]);
        *(short8*)(bfout + n * CHPN + cb) = p;
    }
}

// ---------------- host helpers ----------------

template <int CHP, int CO, int K>
static void conv(const short* fin, const int* rb, const short* wt, short* preact, float* stats,
                 int N, int zrow, hipStream_t stream) {
    dim3 grid((N + 31) / 32);
    hipLaunchKernelGGL((sconv_wc<CHP, CO, K>), grid, dim3(64), 0, stream, fin, rb, wt, preact,
                       stats, N, zrow);
}

template <int COUT, int CHPN, bool F32OUT, bool BFOUT>
static void apply(const short* preact, const float* stats, const float* g, const float* b,
                  float* fout, short* bfout, int N, hipStream_t stream) {
    constexpr int CW = BFOUT ? CHPN : COUT;
    constexpr int CV = CW / 8;
    int blocks = (int)(((long)N * CV + 255) / 256);
    hipLaunchKernelGGL((bn_apply<COUT, CHPN, F32OUT, BFOUT>), dim3(blocks), dim3(256), 0, stream,
                       preact, stats, g, b, fout, bfout, N);
}

extern "C" void kernel_launch(void* const* d_in, const int* in_sizes, int n_in, void* d_out,
                              int out_size, void* d_ws, size_t ws_size, hipStream_t stream) {
    const float* features = (const float*)d_in[0];
    const float* W[14];
    const float* G[14];
    const float* Bb[14];
    for (int i = 0; i < 14; ++i) {
        W[i] = (const float*)d_in[1 + 3 * i];
        G[i] = (const float*)d_in[2 + 3 * i];
        Bb[i] = (const float*)d_in[3 + 3 * i];
    }
    const int* coords0 = (const int*)d_in[43];
    const int* coords1 = (const int*)d_in[44];
    const int* coords2 = (const int*)d_in[45];
    const int* coords3 = (const int*)d_in[46];
    const int* rb0 = (const int*)d_in[47];
    const int* rbc1 = (const int*)d_in[48];
    const int* rb1 = (const int*)d_in[49];
    const int* rbc2 = (const int*)d_in[50];
    const int* rb2 = (const int*)d_in[51];
    const int* rbc3 = (const int*)d_in[52];
    const int* rb3 = (const int*)d_in[53];
    const int* rbc4 = (const int*)d_in[54];

    const int N0 = in_sizes[0] / 4;
    const int N1 = in_sizes[44] / 4;
    const int N2 = in_sizes[45] / 4;
    const int N3 = in_sizes[46] / 4;
    const int N4 = in_sizes[54] / 3;

    float* out = (float*)d_out;
    long off = 0;
    float* xyz0 = out + off; off += (long)N0 * 3;
    float* f0   = out + off; off += (long)N0 * 4;
    float* xyz1 = out + off; off += (long)N1 * 3;
    float* f1   = out + off; off += (long)N1 * 32;
    float* xyz2 = out + off; off += (long)N2 * 3;
    float* f2   = out + off; off += (long)N2 * 64;
    float* xyz3 = out + off; off += (long)N3 * 3;
    float* f3   = out + off; off += (long)N3 * 64;
    float* f4   = out + off;

    long maxN = N0;
    if (N1 > maxN) maxN = N1;
    if (N2 > maxN) maxN = N2;
    if (N3 > maxN) maxN = N3;
    if (N4 > maxN) maxN = N4;
    const int zrow = (int)maxN;

    short* preact = (short*)d_ws;                         // maxN*64 bf16
    float* statsBase = (float*)(preact + (size_t)maxN * 64);  // 14 * NREP * 128 fp32
    short* bfA = (short*)(statsBase + 14 * NREP * 128);   // (maxN+1)*64 bf16
    short* bfB = bfA + (size_t)(maxN + 1) * 64;           // (maxN+1)*64 bf16
    short* wtBase = bfB + (size_t)(maxN + 1) * 64;        // swizzled bf16 weights

    static const int KK[14] = {27, 27, 27, 27, 27, 27, 27, 27, 27, 27, 27, 27, 27, 3};
    static const int CI[14] = {4, 16, 16, 32, 32, 32, 64, 64, 64, 64, 64, 64, 64, 64};
    static const int CO[14] = {16, 16, 32, 32, 32, 64, 64, 64, 64, 64, 64, 64, 64, 64};
    short* WT[14];
    PrepAll pd;
    {
        size_t o = 0;
        int cum = 0;
        for (int l = 0; l < 14; ++l) {
            WT[l] = wtBase + o;
            int chp = CI[l] <= 32 ? 32 : 64;
            pd.src[l] = W[l];
            pd.dst[l] = WT[l];
            pd.CI[l] = CI[l];
            pd.CO[l] = CO[l];
            pd.CHP[l] = chp;
            pd.cum[l] = cum;
            cum += KK[l] * CO[l] * chp;
            o += (size_t)KK[l] * CO[l] * chp;
        }
        pd.cum[14] = cum;
    }

    int nstats = 14 * NREP * 128;
    hipLaunchKernelGGL(zero_kernel, dim3((nstats + 255) / 256), dim3(256), 0, stream, statsBase,
                       nstats);
    hipLaunchKernelGGL(zero_rows_kernel, dim3(1), dim3(256), 0, stream, bfA, bfB, maxN);
    hipLaunchKernelGGL(prep_all_kernel, dim3((pd.cum[14] + 255) / 256), dim3(256), 0, stream, pd);

    hipLaunchKernelGGL(copy_kernel, dim3((N0 * 4 + 255) / 256), dim3(256), 0, stream, features, f0,
                       N0 * 4);
    hipLaunchKernelGGL(xyz_kernel, dim3((N0 + 255) / 256), dim3(256), 0, stream, coords0, xyz0, N0,
                       0.05f, 0.05f, 0.1f);
    hipLaunchKernelGGL(xyz_kernel, dim3((N1 + 255) / 256), dim3(256), 0, stream, coords1, xyz1, N1,
                       0.1f, 0.1f, 0.2f);
    hipLaunchKernelGGL(xyz_kernel, dim3((N2 + 255) / 256), dim3(256), 0, stream, coords2, xyz2, N2,
                       0.2f, 0.2f, 0.4f);
    hipLaunchKernelGGL(xyz_kernel, dim3((N3 + 255) / 256), dim3(256), 0, stream, coords3, xyz3, N3,
                       0.4f, 0.4f, 0.8f);
    hipLaunchKernelGGL(convert_f0, dim3((N0 * 32 + 255) / 256), dim3(256), 0, stream, features,
                       bfA, N0);

    float* st = statsBase;
#define STAT(l) (st + (size_t)(l)*NREP * 128)

    conv<32, 16, 27>(bfA, rb0, WT[0], preact, STAT(0), N0, zrow, stream);
    apply<16, 32, false, true>(preact, STAT(0), G[0], Bb[0], nullptr, bfB, N0, stream);
    conv<32, 16, 27>(bfB, rb0, WT[1], preact, STAT(1), N0, zrow, stream);
    apply<16, 32, false, true>(preact, STAT(1), G[1], Bb[1], nullptr, bfA, N0, stream);
    conv<32, 32, 27>(bfA, rbc1, WT[2], preact, STAT(2), N1, zrow, stream);
    apply<32, 32, true, true>(preact, STAT(2), G[2], Bb[2], f1, bfB, N1, stream);

    conv<32, 32, 27>(bfB, rb1, WT[3], preact, STAT(3), N1, zrow, stream);
    apply<32, 32, false, true>(preact, STAT(3), G[3], Bb[3], nullptr, bfA, N1, stream);
    conv<32, 32, 27>(bfA, rb1, WT[4], preact, STAT(4), N1, zrow, stream);
    apply<32, 32, false, true>(preact, STAT(4), G[4], Bb[4], nullptr, bfB, N1, stream);
    conv<32, 64, 27>(bfB, rbc2, WT[5], preact, STAT(5), N2, zrow, stream);
    apply<64, 64, true, true>(preact, STAT(5), G[5], Bb[5], f2, bfA, N2, stream);

    conv<64, 64, 27>(bfA, rb2, WT[6], preact, STAT(6), N2, zrow, stream);
    apply<64, 64, false, true>(preact, STAT(6), G[6], Bb[6], nullptr, bfB, N2, stream);
    conv<64, 64, 27>(bfB, rb2, WT[7], preact, STAT(7), N2, zrow, stream);
    apply<64, 64, false, true>(preact, STAT(7), G[7], Bb[7], nullptr, bfA, N2, stream);
    conv<64, 64, 27>(bfA, rb2, WT[8], preact, STAT(8), N2, zrow, stream);
    apply<64, 64, false, true>(preact, STAT(8), G[8], Bb[8], nullptr, bfB, N2, stream);
    conv<64, 64, 27>(bfB, rbc3, WT[9], preact, STAT(9), N3, zrow, stream);
    apply<64, 64, true, true>(preact, STAT(9), G[9], Bb[9], f3, bfA, N3, stream);

    conv<64, 64, 27>(bfA, rb3, WT[10], preact, STAT(10), N3, zrow, stream);
    apply<64, 64, false, true>(preact, STAT(10), G[10], Bb[10], nullptr, bfB, N3, stream);
    conv<64, 64, 27>(bfB, rb3, WT[11], preact, STAT(11), N3, zrow, stream);
    apply<64, 64, false, true>(preact, STAT(11), G[11], Bb[11], nullptr, bfA, N3, stream);
    conv<64, 64, 27>(bfA, rb3, WT[12], preact, STAT(12), N3, zrow, stream);
    apply<64, 64, false, true>(preact, STAT(12), G[12], Bb[12], nullptr, bfB, N3, stream);
    conv<64, 64, 3>(bfB, rbc4, WT[13], preact, STAT(13), N4, zrow, stream);
    apply<64, 64, true, false>(preact, STAT(13), G[13], Bb[13], f4, nullptr, N4, stream);
#undef STAT
}

// Round 16
// 650.058 us; speedup vs baseline: 1.0423x; 1.0423x over previous
//
#include <hip/hip_runtime.h>

#define BN_EPS 1e-3f
#define NREP 16  // BN stat replicas

typedef __attribute__((ext_vector_type(8))) short short8;
typedef __attribute__((ext_vector_type(4))) float float4v;

__device__ __forceinline__ short f2bf(float f) {
    unsigned u = __float_as_uint(f);
    unsigned r = (u + 0x7FFFu + ((u >> 16) & 1u)) >> 16;
    return (short)r;
}

__device__ __forceinline__ float bf2f(short s) {
    return __uint_as_float(((unsigned)(unsigned short)s) << 16);
}

// s_waitcnt vmcnt(N) only (N up to 63: bits [3:0] and [15:14])
template <int N>
__device__ __forceinline__ void waitcnt_vm() {
    __builtin_amdgcn_s_waitcnt(0xF70 | (N & 15) | ((N >> 4) << 14));
}

// ---------------- small utility kernels ----------------

__global__ __launch_bounds__(256) void zero_kernel(float* p, int n) {
    int i = blockIdx.x * 256 + threadIdx.x;
    if (i < n) p[i] = 0.f;
}

__global__ __launch_bounds__(256) void copy_kernel(const float* __restrict__ in,
                                                   float* __restrict__ out, int n) {
    int i = blockIdx.x * 256 + threadIdx.x;
    if (i < n) out[i] = in[i];
}

__global__ __launch_bounds__(256) void zero_rows_kernel(short* a, short* b, long maxN) {
    int t = threadIdx.x;
    if (t < 32) a[maxN * 32 + t] = 0;
    else if (t < 96) a[maxN * 64 + (t - 32)] = 0;
    else if (t < 128) b[maxN * 32 + (t - 96)] = 0;
    else if (t < 192) b[maxN * 64 + (t - 128)] = 0;
}

__global__ __launch_bounds__(256) void xyz_kernel(const int* __restrict__ coords,
                                                  float* __restrict__ out, int N,
                                                  float sx, float sy, float sz) {
    int n = blockIdx.x * 256 + threadIdx.x;
    if (n >= N) return;
    int4 c = ((const int4*)coords)[n];
    out[n * 3 + 0] = c.w * sx;
    out[n * 3 + 1] = c.z * sy - 40.0f;
    out[n * 3 + 2] = c.y * sz - 3.0f;
}

__global__ __launch_bounds__(256) void convert_f0(const float* __restrict__ f,
                                                  short* __restrict__ dst, int N) {
    int i = blockIdx.x * 256 + threadIdx.x;
    if (i >= N * 32) return;
    int c = i & 31, n = i >> 5;
    dst[i] = (c < 4) ? f2bf(f[n * 4 + c]) : (short)0;
}

// ---- weight prep: W [K][CI][CO] fp32 -> Wt [K][c*CT+t][quad][l16][8] bf16 ----
struct PrepAll {
    const float* src[14];
    short* dst[14];
    int CI[14];
    int CO[14];
    int CHP[14];
    int cum[15];
};

__global__ __launch_bounds__(256) void prep_all_kernel(PrepAll d) {
    int i = blockIdx.x * 256 + threadIdx.x;
    if (i >= d.cum[14]) return;
    int l = 0;
    while (l < 13 && i >= d.cum[l + 1]) ++l;
    int f = i - d.cum[l];
    int CO = d.CO[l], CI = d.CI[l];
    int NCH = d.CHP[l] / 32, CT = CO / 16;
    int e = f & 7;
    int u = f >> 3;
    int l16 = u & 15;
    int q = (u >> 4) & 3;
    int u2 = u >> 6;
    int t = u2 % CT;
    int c = (u2 / CT) % NCH;
    int k = u2 / (CT * NCH);
    int ci = c * 32 + q * 8 + e;
    int co = t * 16 + l16;
    float v = (ci < CI) ? d.src[l][((size_t)k * CI + ci) * CO + co] : 0.f;
    d.dst[l][f] = f2bf(v);
}

// per-k A fragments for one wave (32 rows x CHP), held in VGPRs
struct ASet {
    short8 v0, v1, v2, v3;  // (mt0,c0) (mt0,c1) (mt1,c0) (mt1,c1)
};

// ---------- wave-compacted MFMA sparse conv (R13 best-known config) ----------
// 64-thread (1-wave) blocks, 32 output rows each. Phase 1: stage wave's rb
// slice [K][32] in LDS (3.5KB), ballot-compact alive taps. Phase 2: register
// pipeline over ONLY alive taps: B DB-ahead (DB=2, or 1 when BF=8 — R15
// proved DB=2 at CO=64 trades occupancy for depth at a net loss), A 2-ahead,
// counted vmcnt per tail regime (never drain mid-loop). Preact stored bf16.
// 15-round mechanism sweep: topology/barriers/rb-staging invariant; depth
// (VGPR- or LDS-paid) regresses via occupancy; FETCH -33% via XCD swizzle
// did not help time (not BW-bound) -> this config is the measured optimum.
template <int CHP, int CO, int K>
__global__ __launch_bounds__(64, 2) void sconv_wc(const short* __restrict__ feat,
                                                  const int* __restrict__ rb,
                                                  const short* __restrict__ Wt,
                                                  short* __restrict__ out,
                                                  float* __restrict__ stats, int N, int zrow) {
    constexpr int NCH = CHP / 32;
    constexpr int CT = CO / 16;
    constexpr int BTILE = CO * CHP;  // shorts
    constexpr int BF = BTILE / 512;  // B loads per tile (1KB coalesced each)
    constexpr int A_ = 2 * NCH;      // A gather loads per tile
    constexpr int DB = (BF >= 8) ? 1 : 2;
    // wait constants (count of loads issued after the last-needed one)
    constexpr int WN2 = 2 * (BF + A_);  // DB=2, d>=2
    constexpr int WN1 = BF + A_;        // DB=2, d==1
    constexpr int WD2 = 2 * A_ + BF;    // DB=1, d>=2
    constexpr int WD1 = A_ + BF;        // DB=1, d==1

    __shared__ int sIdx[K * 32];
    __shared__ int sFlag[K];
    __shared__ int sKl[K];
    __shared__ int sKn;

    const int lane = threadIdx.x & 63;
    const int quad = lane >> 4;
    const int l16 = lane & 15;
    const int m0 = blockIdx.x * 32;

    if (lane < K) sFlag[lane] = 0;
    __syncthreads();
    for (int e = lane; e < K * 32; e += 64) {
        int r = m0 + (e & 31);
        int v = (r < N) ? rb[(size_t)(e >> 5) * N + r] : -1;
        sIdx[e] = v;
        if (v >= 0) sFlag[e >> 5] = 1;  // benign race: same value
    }
    __syncthreads();
    {
        int f = (lane < K) ? sFlag[lane] : 0;
        unsigned long long m = __ballot(f != 0);
        if (f) sKl[__popcll(m & ((1ull << lane) - 1ull))] = lane;
        if (lane == 0) sKn = (int)__popcll(m);
    }
    __syncthreads();
    const int nk = sKn;

    const short* fquad = feat + quad * 8;

    struct BSet {
        short8 f[BF];
    };
    auto issueB = [&](int kp) {
        BSet b;
        const short* wk = Wt + (size_t)kp * BTILE;
#pragma unroll
        for (int j = 0; j < BF; ++j)
            b.f[j] = *(const short8*)(wk + ((j * 64) + quad * 16 + l16) * 8);
        return b;
    };
    auto issueA = [&](int kp) {
        ASet s;
        int i0 = sIdx[kp * 32 + l16];
        int i1 = sIdx[kp * 32 + 16 + l16];
        const short* q0 = fquad + (size_t)(i0 < 0 ? zrow : i0) * CHP;
        const short* q1 = fquad + (size_t)(i1 < 0 ? zrow : i1) * CHP;
        s.v0 = *(const short8*)q0;
        s.v2 = *(const short8*)q1;
        if constexpr (NCH == 2) {
            s.v1 = *(const short8*)(q0 + 32);
            s.v3 = *(const short8*)(q1 + 32);
        } else {
            s.v1 = (short8)0;
            s.v3 = (short8)0;
        }
        return s;
    };

    float4v acc[2][CT];
#pragma unroll
    for (int mt = 0; mt < 2; ++mt)
#pragma unroll
        for (int t = 0; t < CT; ++t) acc[mt][t] = (float4v)0.f;

    // ---- prologue (interleaved so steady wait constants hold from i=0) ----
    BSet bA{}, bB{}, bC{};
    ASet sA{}, sB{}, sC{};
    if (nk > 0) {
        bA = issueB(sKl[0]);
        sA = issueA(sKl[0]);
    }
    if (DB == 2 && nk > 1) bB = issueB(sKl[1]);
    if (nk > 1) sB = issueA(sKl[1]);

#pragma unroll 1
    for (int i = 0; i < nk; ++i) {
        if constexpr (DB == 2) {
            if (i + 2 < nk) bC = issueB(sKl[i + 2]);
        } else {
            if (i + 1 < nk) bB = issueB(sKl[i + 1]);
        }
        if (i + 2 < nk) sC = issueA(sKl[i + 2]);
        const int d = nk - 1 - i;
        if constexpr (DB == 2) {
            if (d >= 2) waitcnt_vm<WN2>();
            else if (d == 1) waitcnt_vm<WN1>();
            else waitcnt_vm<0>();
        } else {
            if (d >= 2) waitcnt_vm<WD2>();
            else if (d == 1) waitcnt_vm<WD1>();
            else waitcnt_vm<0>();
        }
#pragma unroll
        for (int c = 0; c < NCH; ++c) {
#pragma unroll
            for (int t = 0; t < CT; ++t) {
                short8 bf = bA.f[c * CT + t];
#pragma unroll
                for (int mt = 0; mt < 2; ++mt) {
                    short8 af = (mt == 0) ? ((c == 0) ? sA.v0 : sA.v1)
                                          : ((c == 0) ? sA.v2 : sA.v3);
                    acc[mt][t] =
                        __builtin_amdgcn_mfma_f32_16x16x32_bf16(af, bf, acc[mt][t], 0, 0, 0);
                }
            }
        }
        if constexpr (DB == 2) {
            bA = bB;
            bB = bC;
        } else {
            bA = bB;
        }
        sA = sB;
        sB = sC;
    }

    // stores: D layout col = lane&15, row = quad*4 + reg. bf16 preact.
#pragma unroll
    for (int mt = 0; mt < 2; ++mt)
#pragma unroll
        for (int t = 0; t < CT; ++t) {
            int col = t * 16 + l16;
#pragma unroll
            for (int r = 0; r < 4; ++r) {
                int orow = m0 + mt * 16 + quad * 4 + r;
                if (orow < N) out[(size_t)orow * CO + col] = f2bf(acc[mt][t][r]);
            }
        }

    // per-wave BN stats (fp32 acc) -> replica atomics.
    // (OOB rows and -1 gathers hit the zero row, so their acc entries are 0)
    float* st = stats + (size_t)(blockIdx.x & (NREP - 1)) * 128;
#pragma unroll
    for (int t = 0; t < CT; ++t) {
        float s = 0.f, ss = 0.f;
#pragma unroll
        for (int mt = 0; mt < 2; ++mt)
#pragma unroll
            for (int r = 0; r < 4; ++r) {
                float v = acc[mt][t][r];
                s += v;
                ss += v * v;
            }
        s += __shfl_xor(s, 16);
        s += __shfl_xor(s, 32);
        ss += __shfl_xor(ss, 16);
        ss += __shfl_xor(ss, 32);
        if (lane < 16) {
            atomicAdd(&st[t * 16 + lane], s);
            atomicAdd(&st[64 + t * 16 + lane], ss);
        }
    }
}

// ---------------- BN apply + ReLU, 8-wide vectorized (bf16 preact in) ------------
template <int COUT, int CHPN, bool F32OUT, bool BFOUT>
__global__ __launch_bounds__(256) void bn_apply(const short* __restrict__ x,
                                                const float* __restrict__ stats,
                                                const float* __restrict__ g,
                                                const float* __restrict__ b,
                                                float* __restrict__ fout,
                                                short* __restrict__ bfout, int N) {
    constexpr int CW = BFOUT ? CHPN : COUT;
    constexpr int CV = CW / 8;  // 8-channel groups per row
    __shared__ float ssc[COUT];
    __shared__ float ssh[COUT];
    int tid = threadIdx.x;
    if (tid < COUT) {
        float s = 0.f, q = 0.f;
#pragma unroll
        for (int r = 0; r < NREP; ++r) {
            s += stats[r * 128 + tid];
            q += stats[r * 128 + 64 + tid];
        }
        float inv = 1.0f / (float)N;
        float m = s * inv;
        float v = q * inv - m * m;
        float sc = g[tid] / sqrtf(v + BN_EPS);
        ssc[tid] = sc;
        ssh[tid] = b[tid] - m * sc;
    }
    __syncthreads();
    long i = (long)blockIdx.x * 256 + tid;
    if (i >= (long)N * CV) return;
    int c8 = (int)(i % CV);
    long n = i / CV;
    int cb = c8 * 8;
    float y[8];
#pragma unroll
    for (int j = 0; j < 8; ++j) y[j] = 0.f;
    if (cb < COUT) {
        short8 xv = *(const short8*)(x + n * COUT + cb);
#pragma unroll
        for (int j = 0; j < 8; ++j)
            y[j] = fmaxf(bf2f(xv[j]) * ssc[cb + j] + ssh[cb + j], 0.f);
        if constexpr (F32OUT) {
            float* fo = fout + n * COUT + cb;
            if ((((unsigned long long)fout) & 15ull) == 0) {  // uniform branch
                float4v o0, o1;
#pragma unroll
                for (int j = 0; j < 4; ++j) {
                    o0[j] = y[j];
                    o1[j] = y[4 + j];
                }
                ((float4v*)fo)[0] = o0;
                ((float4v*)fo)[1] = o1;
            } else {
#pragma unroll
                for (int j = 0; j < 8; ++j) fo[j] = y[j];
            }
        }
    }
    if constexpr (BFOUT) {
        short8 p;
#pragma unroll
        for (int j = 0; j < 8; ++j) p[j] = f2bf(y[j]);
        *(short8*)(bfout + n * CHPN + cb) = p;
    }
}

// ---------------- host helpers ----------------

template <int CHP, int CO, int K>
static void conv(const short* fin, const int* rb, const short* wt, short* preact, float* stats,
                 int N, int zrow, hipStream_t stream) {
    dim3 grid((N + 31) / 32);
    hipLaunchKernelGGL((sconv_wc<CHP, CO, K>), grid, dim3(64), 0, stream, fin, rb, wt, preact,
                       stats, N, zrow);
}

template <int COUT, int CHPN, bool F32OUT, bool BFOUT>
static void apply(const short* preact, const float* stats, const float* g, const float* b,
                  float* fout, short* bfout, int N, hipStream_t stream) {
    constexpr int CW = BFOUT ? CHPN : COUT;
    constexpr int CV = CW / 8;
    int blocks = (int)(((long)N * CV + 255) / 256);
    hipLaunchKernelGGL((bn_apply<COUT, CHPN, F32OUT, BFOUT>), dim3(blocks), dim3(256), 0, stream,
                       preact, stats, g, b, fout, bfout, N);
}

extern "C" void kernel_launch(void* const* d_in, const int* in_sizes, int n_in, void* d_out,
                              int out_size, void* d_ws, size_t ws_size, hipStream_t stream) {
    const float* features = (const float*)d_in[0];
    const float* W[14];
    const float* G[14];
    const float* Bb[14];
    for (int i = 0; i < 14; ++i) {
        W[i] = (const float*)d_in[1 + 3 * i];
        G[i] = (const float*)d_in[2 + 3 * i];
        Bb[i] = (const float*)d_in[3 + 3 * i];
    }
    const int* coords0 = (const int*)d_in[43];
    const int* coords1 = (const int*)d_in[44];
    const int* coords2 = (const int*)d_in[45];
    const int* coords3 = (const int*)d_in[46];
    const int* rb0 = (const int*)d_in[47];
    const int* rbc1 = (const int*)d_in[48];
    const int* rb1 = (const int*)d_in[49];
    const int* rbc2 = (const int*)d_in[50];
    const int* rb2 = (const int*)d_in[51];
    const int* rbc3 = (const int*)d_in[52];
    const int* rb3 = (const int*)d_in[53];
    const int* rbc4 = (const int*)d_in[54];

    const int N0 = in_sizes[0] / 4;
    const int N1 = in_sizes[44] / 4;
    const int N2 = in_sizes[45] / 4;
    const int N3 = in_sizes[46] / 4;
    const int N4 = in_sizes[54] / 3;

    float* out = (float*)d_out;
    long off = 0;
    float* xyz0 = out + off; off += (long)N0 * 3;
    float* f0   = out + off; off += (long)N0 * 4;
    float* xyz1 = out + off; off += (long)N1 * 3;
    float* f1   = out + off; off += (long)N1 * 32;
    float* xyz2 = out + off; off += (long)N2 * 3;
    float* f2   = out + off; off += (long)N2 * 64;
    float* xyz3 = out + off; off += (long)N3 * 3;
    float* f3   = out + off; off += (long)N3 * 64;
    float* f4   = out + off;

    long maxN = N0;
    if (N1 > maxN) maxN = N1;
    if (N2 > maxN) maxN = N2;
    if (N3 > maxN) maxN = N3;
    if (N4 > maxN) maxN = N4;
    const int zrow = (int)maxN;

    short* preact = (short*)d_ws;                         // maxN*64 bf16
    float* statsBase = (float*)(preact + (size_t)maxN * 64);  // 14 * NREP * 128 fp32
    short* bfA = (short*)(statsBase + 14 * NREP * 128);   // (maxN+1)*64 bf16
    short* bfB = bfA + (size_t)(maxN + 1) * 64;           // (maxN+1)*64 bf16
    short* wtBase = bfB + (size_t)(maxN + 1) * 64;        // swizzled bf16 weights

    static const int KK[14] = {27, 27, 27, 27, 27, 27, 27, 27, 27, 27, 27, 27, 27, 3};
    static const int CI[14] = {4, 16, 16, 32, 32, 32, 64, 64, 64, 64, 64, 64, 64, 64};
    static const int CO[14] = {16, 16, 32, 32, 32, 64, 64, 64, 64, 64, 64, 64, 64, 64};
    short* WT[14];
    PrepAll pd;
    {
        size_t o = 0;
        int cum = 0;
        for (int l = 0; l < 14; ++l) {
            WT[l] = wtBase + o;
            int chp = CI[l] <= 32 ? 32 : 64;
            pd.src[l] = W[l];
            pd.dst[l] = WT[l];
            pd.CI[l] = CI[l];
            pd.CO[l] = CO[l];
            pd.CHP[l] = chp;
            pd.cum[l] = cum;
            cum += KK[l] * CO[l] * chp;
            o += (size_t)KK[l] * CO[l] * chp;
        }
        pd.cum[14] = cum;
    }

    int nstats = 14 * NREP * 128;
    hipLaunchKernelGGL(zero_kernel, dim3((nstats + 255) / 256), dim3(256), 0, stream, statsBase,
                       nstats);
    hipLaunchKernelGGL(zero_rows_kernel, dim3(1), dim3(256), 0, stream, bfA, bfB, maxN);
    hipLaunchKernelGGL(prep_all_kernel, dim3((pd.cum[14] + 255) / 256), dim3(256), 0, stream, pd);

    hipLaunchKernelGGL(copy_kernel, dim3((N0 * 4 + 255) / 256), dim3(256), 0, stream, features, f0,
                       N0 * 4);
    hipLaunchKernelGGL(xyz_kernel, dim3((N0 + 255) / 256), dim3(256), 0, stream, coords0, xyz0, N0,
                       0.05f, 0.05f, 0.1f);
    hipLaunchKernelGGL(xyz_kernel, dim3((N1 + 255) / 256), dim3(256), 0, stream, coords1, xyz1, N1,
                       0.1f, 0.1f, 0.2f);
    hipLaunchKernelGGL(xyz_kernel, dim3((N2 + 255) / 256), dim3(256), 0, stream, coords2, xyz2, N2,
                       0.2f, 0.2f, 0.4f);
    hipLaunchKernelGGL(xyz_kernel, dim3((N3 + 255) / 256), dim3(256), 0, stream, coords3, xyz3, N3,
                       0.4f, 0.4f, 0.8f);
    hipLaunchKernelGGL(convert_f0, dim3((N0 * 32 + 255) / 256), dim3(256), 0, stream, features,
                       bfA, N0);

    float* st = statsBase;
#define STAT(l) (st + (size_t)(l)*NREP * 128)

    conv<32, 16, 27>(bfA, rb0, WT[0], preact, STAT(0), N0, zrow, stream);
    apply<16, 32, false, true>(preact, STAT(0), G[0], Bb[0], nullptr, bfB, N0, stream);
    conv<32, 16, 27>(bfB, rb0, WT[1], preact, STAT(1), N0, zrow, stream);
    apply<16, 32, false, true>(preact, STAT(1), G[1], Bb[1], nullptr, bfA, N0, stream);
    conv<32, 32, 27>(bfA, rbc1, WT[2], preact, STAT(2), N1, zrow, stream);
    apply<32, 32, true, true>(preact, STAT(2), G[2], Bb[2], f1, bfB, N1, stream);

    conv<32, 32, 27>(bfB, rb1, WT[3], preact, STAT(3), N1, zrow, stream);
    apply<32, 32, false, true>(preact, STAT(3), G[3], Bb[3], nullptr, bfA, N1, stream);
    conv<32, 32, 27>(bfA, rb1, WT[4], preact, STAT(4), N1, zrow, stream);
    apply<32, 32, false, true>(preact, STAT(4), G[4], Bb[4], nullptr, bfB, N1, stream);
    conv<32, 64, 27>(bfB, rbc2, WT[5], preact, STAT(5), N2, zrow, stream);
    apply<64, 64, true, true>(preact, STAT(5), G[5], Bb[5], f2, bfA, N2, stream);

    conv<64, 64, 27>(bfA, rb2, WT[6], preact, STAT(6), N2, zrow, stream);
    apply<64, 64, false, true>(preact, STAT(6), G[6], Bb[6], nullptr, bfB, N2, stream);
    conv<64, 64, 27>(bfB, rb2, WT[7], preact, STAT(7), N2, zrow, stream);
    apply<64, 64, false, true>(preact, STAT(7), G[7], Bb[7], nullptr, bfA, N2, stream);
    conv<64, 64, 27>(bfA, rb2, WT[8], preact, STAT(8), N2, zrow, stream);
    apply<64, 64, false, true>(preact, STAT(8), G[8], Bb[8], nullptr, bfB, N2, stream);
    conv<64, 64, 27>(bfB, rbc3, WT[9], preact, STAT(9), N3, zrow, stream);
    apply<64, 64, true, true>(preact, STAT(9), G[9], Bb[9], f3, bfA, N3, stream);

    conv<64, 64, 27>(bfA, rb3, WT[10], preact, STAT(10), N3, zrow, stream);
    apply<64, 64, false, true>(preact, STAT(10), G[10], Bb[10], nullptr, bfB, N3, stream);
    conv<64, 64, 27>(bfB, rb3, WT[11], preact, STAT(11), N3, zrow, stream);
    apply<64, 64, false, true>(preact, STAT(11), G[11], Bb[11], nullptr, bfA, N3, stream);
    conv<64, 64, 27>(bfA, rb3, WT[12], preact, STAT(12), N3, zrow, stream);
    apply<64, 64, false, true>(preact, STAT(12), G[12], Bb[12], nullptr, bfB, N3, stream);
    conv<64, 64, 3>(bfB, rbc4, WT[13], preact, STAT(13), N4, zrow, stream);
    apply<64, 64, true, false>(preact, STAT(13), G[13], Bb[13], f4, nullptr, N4, stream);
#undef STAT
}